// Round 1
// baseline (292.252 us; speedup 1.0000x reference)
//
#include <hip/hip_runtime.h>
#include <math.h>

#define NW 12
#define NL 4
#define DIM 4096
#define OUTD 8

typedef float2 c32;

__device__ __forceinline__ c32 cmul(c32 a, c32 b) {
    return make_float2(a.x*b.x - a.y*b.y, a.x*b.y + a.y*b.x);
}
__device__ __forceinline__ c32 cadd(c32 a, c32 b) {
    return make_float2(a.x + b.x, a.y + b.y);
}
// pad every 16 complex by 1 to break stride-16 bank conflicts in the low-bit pass
__device__ __forceinline__ int PHYS(int i) { return i + (i >> 4); }

__global__ __launch_bounds__(256) void qnn_kernel(const float* __restrict__ x,
                                                  const float* __restrict__ w,
                                                  float* __restrict__ out)
{
    __shared__ c32 st[DIM + (DIM >> 4)];   // 4352 * 8B = 34 KB
    __shared__ c32 um[NL * NW][4];         // 48 fused 2x2 complex gates
    __shared__ float sred[32];

    const int b = blockIdx.x;
    const int t = threadIdx.x;

    // ---- build fused per-(layer,wire) gate: U = Rz(w2)*Ry(w1)*Rx(w0)*Enc ----
    if (t < NL * NW) {
        const int layer = t / NW, wire = t % NW;
        const float ang = (wire & 1) ? x[b * 2 + 1] : x[b * 2 + 0];
        float se, ce;
        sincosf(0.5f * ang, &se, &ce);
        c32 E0, E1, E2, E3;
        if ((wire & 1) == 0) {           // Rx(x0): [[c,-is],[-is,c]]
            E0 = make_float2(ce, 0.f);  E1 = make_float2(0.f, -se);
            E2 = make_float2(0.f, -se); E3 = make_float2(ce, 0.f);
        } else {                          // Ry(x1): [[c,-s],[s,c]]
            E0 = make_float2(ce, 0.f);  E1 = make_float2(-se, 0.f);
            E2 = make_float2(se, 0.f);  E3 = make_float2(ce, 0.f);
        }
        const float w0 = w[(layer * NW + wire) * 3 + 0];
        const float w1 = w[(layer * NW + wire) * 3 + 1];
        const float w2 = w[(layer * NW + wire) * 3 + 2];
        // A = Rx(w0) * E
        float s0, c0; sincosf(0.5f * w0, &s0, &c0);
        const c32 rx00 = make_float2(c0, 0.f), rx01 = make_float2(0.f, -s0);
        c32 A0 = cadd(cmul(rx00, E0), cmul(rx01, E2));
        c32 A1 = cadd(cmul(rx00, E1), cmul(rx01, E3));
        c32 A2 = cadd(cmul(rx01, E0), cmul(rx00, E2));
        c32 A3 = cadd(cmul(rx01, E1), cmul(rx00, E3));
        // B = Ry(w1) * A   (Ry is real)
        float s1, c1; sincosf(0.5f * w1, &s1, &c1);
        c32 B0 = make_float2(c1 * A0.x - s1 * A2.x, c1 * A0.y - s1 * A2.y);
        c32 B1 = make_float2(c1 * A1.x - s1 * A3.x, c1 * A1.y - s1 * A3.y);
        c32 B2 = make_float2(s1 * A0.x + c1 * A2.x, s1 * A0.y + c1 * A2.y);
        c32 B3 = make_float2(s1 * A1.x + c1 * A3.x, s1 * A1.y + c1 * A3.y);
        // U = Rz(w2) * B : row0 *= e^{-i w2/2}, row1 *= e^{+i w2/2}
        float s2, c2; sincosf(0.5f * w2, &s2, &c2);
        const c32 em = make_float2(c2, -s2), ep = make_float2(c2, s2);
        um[t][0] = cmul(em, B0); um[t][1] = cmul(em, B1);
        um[t][2] = cmul(ep, B2); um[t][3] = cmul(ep, B3);
    }

    // ---- init state |0...0> ----
    #pragma unroll
    for (int j = 0; j < 16; ++j) st[PHYS(t * 16 + j)] = make_float2(0.f, 0.f);
    if (t == 0) st[0] = make_float2(1.f, 0.f);
    __syncthreads();

    c32 a[16];

    for (int layer = 0; layer < NL; ++layer) {
        // 3 gate passes: pass p handles wires 4p..4p+3 (index bits [8-4p .. 11-4p])
        #pragma unroll
        for (int p = 0; p < 3; ++p) {
            const int shift = 8 - 4 * p;
            const int base = ((t >> shift) << (shift + 4)) | (t & ((1 << shift) - 1));
            #pragma unroll
            for (int m = 0; m < 16; ++m) a[m] = st[PHYS(base | (m << shift))];

            #pragma unroll
            for (int q = 0; q < 4; ++q) {
                const c32 u00 = um[layer * NW + 4 * p + q][0];
                const c32 u01 = um[layer * NW + 4 * p + q][1];
                const c32 u10 = um[layer * NW + 4 * p + q][2];
                const c32 u11 = um[layer * NW + 4 * p + q][3];
                const int mask = 8 >> q;   // wire 4p+q -> local bit 3-q
                #pragma unroll
                for (int m = 0; m < 16; ++m) {
                    if (m & mask) continue;
                    const c32 v0 = a[m], v1 = a[m | mask];
                    a[m]        = cadd(cmul(u00, v0), cmul(u01, v1));
                    a[m | mask] = cadd(cmul(u10, v0), cmul(u11, v1));
                }
            }
            #pragma unroll
            for (int m = 0; m < 16; ++m) st[PHYS(base | (m << shift))] = a[m];
            __syncthreads();
        }

        // CNOT chain = permutation; gather form: new[m] = old[m ^ (m>>1)]
        #pragma unroll
        for (int j = 0; j < 16; ++j) {
            const int n = t * 16 + j;
            a[j] = st[PHYS(n ^ (n >> 1))];
        }
        __syncthreads();
        #pragma unroll
        for (int j = 0; j < 16; ++j) st[PHYS(t * 16 + j)] = a[j];
        __syncthreads();
    }

    // ---- reduction: 8 Z expectations ----
    // amps t*16..t*16+15 share index bits 11..4 == t, so one sign vector per thread
    float ssum = 0.f;
    #pragma unroll
    for (int j = 0; j < 16; ++j) {
        const c32 v = st[PHYS(t * 16 + j)];
        ssum += v.x * v.x + v.y * v.y;
    }
    const int lane = t & 63, wv = t >> 6;
    #pragma unroll
    for (int i = 0; i < 8; ++i) {
        float wval = ((t >> (7 - i)) & 1) ? -ssum : ssum;
        #pragma unroll
        for (int off = 32; off; off >>= 1) wval += __shfl_xor(wval, off, 64);
        if (lane == 0) sred[wv * 8 + i] = wval;
    }
    __syncthreads();
    if (t < 8) {
        const float r = sred[t] + sred[8 + t] + sred[16 + t] + sred[24 + t];
        out[b * 8 + t] = r * 3.14159265358979323846f;
    }
}

extern "C" void kernel_launch(void* const* d_in, const int* in_sizes, int n_in,
                              void* d_out, int out_size, void* d_ws, size_t ws_size,
                              hipStream_t stream) {
    const float* x = (const float*)d_in[0];   // [4096, 2]
    const float* w = (const float*)d_in[1];   // [4, 12, 3]
    float* out = (float*)d_out;               // [4096, 8]
    qnn_kernel<<<4096, 256, 0, stream>>>(x, w, out);
}

// Round 2
// 194.476 us; speedup vs baseline: 1.5028x; 1.5028x over previous
//
#include <hip/hip_runtime.h>
#include <math.h>

#define NW 12
#define NL 4
#define DIM 4096

typedef float v2f __attribute__((ext_vector_type(2)));
typedef float2 c32;

__device__ __forceinline__ c32 cmul(c32 a, c32 b) {
    return make_float2(a.x*b.x - a.y*b.y, a.x*b.y + a.y*b.x);
}
__device__ __forceinline__ c32 cadd(c32 a, c32 b) {
    return make_float2(a.x + b.x, a.y + b.y);
}

// pad 2 float2 per 16 -> thread stride 18 amps = 144 B (16B aligned, even bank spread)
__device__ __forceinline__ int PHYS(int i) { return i + ((i >> 4) << 1); }

struct alignas(16) G { float c00x,c00y,c01x,c01y,c10x,c10y,c11x,c11y; };

// butterfly on two pair-regs (local bit mask != 8): out0=u00*v0+u01*v1; out1=u10*v0+u11*v1
__device__ __forceinline__ void bf_pair(v2f& xr, v2f& xi, v2f& yr, v2f& yi, const G& g){
    v2f ar = xr, ai = xi, br = yr, bi = yi;
    xr = ar*g.c00x - ai*g.c00y + br*g.c01x - bi*g.c01y;
    xi = ai*g.c00x + ar*g.c00y + bi*g.c01x + br*g.c01y;
    yr = ar*g.c10x - ai*g.c10y + br*g.c11x - bi*g.c11y;
    yi = ai*g.c10x + ar*g.c10y + bi*g.c11x + br*g.c11y;
}
// butterfly across the packing halves (mask == 8): lo/hi of same reg are the pair
__device__ __forceinline__ void bf_cross(v2f& xr, v2f& xi, const G& g){
    v2f K0x; K0x.x = g.c00x; K0x.y = g.c10x;
    v2f K0y; K0y.x = g.c00y; K0y.y = g.c10y;
    v2f K1x; K1x.x = g.c01x; K1x.y = g.c11x;
    v2f K1y; K1y.x = g.c01y; K1y.y = g.c11y;
    v2f rl; rl.x = xr.x; rl.y = xr.x;
    v2f rh; rh.x = xr.y; rh.y = xr.y;
    v2f il; il.x = xi.x; il.y = xi.x;
    v2f ih; ih.x = xi.y; ih.y = xi.y;
    xr = K0x*rl - K0y*il + K1x*rh - K1y*ih;
    xi = K0x*il + K0y*rl + K1x*ih + K1y*rh;
}
__device__ __forceinline__ void gate_local(v2f re[8], v2f im[8], const G& g, const int m){
    if (m == 8) {
        #pragma unroll
        for (int r = 0; r < 8; ++r) bf_cross(re[r], im[r], g);
    } else {
        #pragma unroll
        for (int r = 0; r < 8; ++r)
            if (!(r & m)) bf_pair(re[r], im[r], re[r|m], im[r|m], g);
    }
}
// butterfly across a lane bit: my amp j pairs with partner's amp j
__device__ __forceinline__ void gate_shfl(v2f re[8], v2f im[8], const G& g, const int LM, const int side){
    const float cAx = side ? g.c11x : g.c00x;
    const float cAy = side ? g.c11y : g.c00y;
    const float cBx = side ? g.c10x : g.c01x;
    const float cBy = side ? g.c10y : g.c01y;
    #pragma unroll
    for (int r = 0; r < 8; ++r) {
        v2f tr, ti;
        tr.x = __shfl_xor(re[r].x, LM, 64);
        tr.y = __shfl_xor(re[r].y, LM, 64);
        ti.x = __shfl_xor(im[r].x, LM, 64);
        ti.y = __shfl_xor(im[r].y, LM, 64);
        v2f ar = re[r], ai = im[r];
        re[r] = ar*cAx - ai*cAy + tr*cBx - ti*cBy;
        im[r] = ai*cAx + ar*cAy + ti*cBx + tr*cBy;
    }
}

__global__ __launch_bounds__(256) void qnn_kernel(const float* __restrict__ x,
                                                  const float* __restrict__ w,
                                                  float* __restrict__ out)
{
    __shared__ float2 st[DIM + (DIM >> 3)];  // 4608 * 8 B = 36 KB
    __shared__ G ug[NL * NW];
    __shared__ float sred[32];

    const int b = blockIdx.x;
    const int t = threadIdx.x;

    // ---- build fused per-(layer,wire) gate: U = Rz(w2)*Ry(w1)*Rx(w0)*Enc ----
    if (t < NL * NW) {
        const int wire = t % NW;
        const float ang = (wire & 1) ? x[b * 2 + 1] : x[b * 2 + 0];
        float se, ce;
        sincosf(0.5f * ang, &se, &ce);
        c32 E0, E1, E2, E3;
        if ((wire & 1) == 0) {            // Rx(x0)
            E0 = make_float2(ce, 0.f);  E1 = make_float2(0.f, -se);
            E2 = make_float2(0.f, -se); E3 = make_float2(ce, 0.f);
        } else {                          // Ry(x1)
            E0 = make_float2(ce, 0.f);  E1 = make_float2(-se, 0.f);
            E2 = make_float2(se, 0.f);  E3 = make_float2(ce, 0.f);
        }
        const float w0 = w[t * 3 + 0];
        const float w1 = w[t * 3 + 1];
        const float w2 = w[t * 3 + 2];
        float s0, c0; sincosf(0.5f * w0, &s0, &c0);
        const c32 rx00 = make_float2(c0, 0.f), rx01 = make_float2(0.f, -s0);
        c32 A0 = cadd(cmul(rx00, E0), cmul(rx01, E2));
        c32 A1 = cadd(cmul(rx00, E1), cmul(rx01, E3));
        c32 A2 = cadd(cmul(rx01, E0), cmul(rx00, E2));
        c32 A3 = cadd(cmul(rx01, E1), cmul(rx00, E3));
        float s1, c1; sincosf(0.5f * w1, &s1, &c1);
        c32 B0 = make_float2(c1*A0.x - s1*A2.x, c1*A0.y - s1*A2.y);
        c32 B1 = make_float2(c1*A1.x - s1*A3.x, c1*A1.y - s1*A3.y);
        c32 B2 = make_float2(s1*A0.x + c1*A2.x, s1*A0.y + c1*A2.y);
        c32 B3 = make_float2(s1*A1.x + c1*A3.x, s1*A1.y + c1*A3.y);
        float s2, c2; sincosf(0.5f * w2, &s2, &c2);
        const c32 em = make_float2(c2, -s2), ep = make_float2(c2, s2);
        const c32 u00 = cmul(em, B0), u01 = cmul(em, B1);
        const c32 u10 = cmul(ep, B2), u11 = cmul(ep, B3);
        G gg; gg.c00x=u00.x; gg.c00y=u00.y; gg.c01x=u01.x; gg.c01y=u01.y;
              gg.c10x=u10.x; gg.c10y=u10.y; gg.c11x=u11.x; gg.c11y=u11.y;
        ug[t] = gg;
    }
    __syncthreads();

    // ---- layer 0 analytically: product state then CNOT (gray) baked into A layout ----
    // state regs: layout A (n = t*16 + j), pair-packing along j bit3:
    // re[r].x = Re amp(j=r), re[r].y = Re amp(j=r+8)
    v2f re[8], im[8];
    {
        const int u = (t ^ (t >> 1)) & 255;     // m bits 11..4 (wires 0..7)
        c32 Pb = make_float2(1.f, 0.f);
        #pragma unroll
        for (int wq = 0; wq < 8; ++wq) {
            const G& gg = ug[wq];
            const int bit = (u >> (7 - wq)) & 1;
            const c32 c = bit ? make_float2(gg.c10x, gg.c10y)
                              : make_float2(gg.c00x, gg.c00y);
            Pb = cmul(Pb, c);
        }
        c32 c8[2]  = { make_float2(ug[8].c00x,  ug[8].c00y),  make_float2(ug[8].c10x,  ug[8].c10y) };
        c32 c9[2]  = { make_float2(ug[9].c00x,  ug[9].c00y),  make_float2(ug[9].c10x,  ug[9].c10y) };
        c32 cA[2]  = { make_float2(ug[10].c00x, ug[10].c00y), make_float2(ug[10].c10x, ug[10].c10y) };
        c32 cB[2]  = { make_float2(ug[11].c00x, ug[11].c00y), make_float2(ug[11].c10x, ug[11].c10y) };
        c32 L2[4], T4[4];
        #pragma unroll
        for (int k = 0; k < 4; ++k) {
            L2[k] = cmul(c8[(k >> 1) & 1], c9[k & 1]);
            T4[k] = cmul(cA[(k >> 1) & 1], cB[k & 1]);
        }
        const int t0 = t & 1;
        #pragma unroll
        for (int j = 0; j < 16; ++j) {
            const int l0 = j ^ (j >> 1);        // low 4 bits before t0 flip of bit3
            const c32 Lsel = t0 ? L2[((l0 >> 2) & 3) ^ 2] : L2[(l0 >> 2) & 3];
            const c32 amp = cmul(Pb, cmul(Lsel, T4[l0 & 3]));
            const int r = j & 7;
            if (j < 8) { re[r].x = amp.x; im[r].x = amp.y; }
            else       { re[r].y = amp.x; im[r].y = amp.y; }
        }
    }

    // ---- layers 1..3 ----
    for (int layer = 1; layer < NL; ++layer) {
        const int gbase = layer * NW;
        // layout A: wires 8..11 live in local bits 3..0
        gate_local(re, im, ug[gbase + 8],  8);
        gate_local(re, im, ug[gbase + 9],  4);
        gate_local(re, im, ug[gbase + 10], 2);
        gate_local(re, im, ug[gbase + 11], 1);
        // wires 4..7 live in t bits 3..0 (within-wave)
        gate_shfl(re, im, ug[gbase + 4], 8, (t >> 3) & 1);
        gate_shfl(re, im, ug[gbase + 5], 4, (t >> 2) & 1);
        gate_shfl(re, im, ug[gbase + 6], 2, (t >> 1) & 1);
        gate_shfl(re, im, ug[gbase + 7], 1,  t & 1);
        // RT1: A -> B (wires 0..3 need t bits 7..4 = cross-wave)
        __syncthreads();   // protect previous layer's gather reads
        #pragma unroll
        for (int r = 0; r < 8; ++r) {
            st[PHYS((t << 4) | r)]       = make_float2(re[r].x, im[r].x);
            st[PHYS((t << 4) | (r + 8))] = make_float2(re[r].y, im[r].y);
        }
        __syncthreads();
        #pragma unroll
        for (int r = 0; r < 8; ++r) {
            const float2 lo = st[PHYS((r << 8) | t)];
            const float2 hi = st[PHYS(((r + 8) << 8) | t)];
            v2f vr; vr.x = lo.x; vr.y = hi.x; re[r] = vr;
            v2f vi; vi.x = lo.y; vi.y = hi.y; im[r] = vi;
        }
        // layout B: wires 0..3 live in local bits 3..0
        gate_local(re, im, ug[gbase + 0], 8);
        gate_local(re, im, ug[gbase + 1], 4);
        gate_local(re, im, ug[gbase + 2], 2);
        gate_local(re, im, ug[gbase + 3], 1);
        if (layer < NL - 1) {
            // RT2: B -> A with CNOT perm fused (new[n] = old[n^(n>>1)]).
            // write-back hits exactly the slots this thread read in RT1 -> no sync needed
            #pragma unroll
            for (int r = 0; r < 8; ++r) {
                st[PHYS((r << 8) | t)]       = make_float2(re[r].x, im[r].x);
                st[PHYS(((r + 8) << 8) | t)] = make_float2(re[r].y, im[r].y);
            }
            __syncthreads();
            #pragma unroll
            for (int r = 0; r < 8; ++r) {
                const int nlo = (t << 4) | r;
                const int nhi = (t << 4) | (r + 8);
                const float2 lo = st[PHYS(nlo ^ (nlo >> 1))];
                const float2 hi = st[PHYS(nhi ^ (nhi >> 1))];
                v2f vr; vr.x = lo.x; vr.y = hi.x; re[r] = vr;
                v2f vi; vi.x = lo.y; vi.y = hi.y; im[r] = vi;
            }
        }
    }

    // ---- reduction; final CNOT folded into signs: m = g^{-1}(n) => prefix-XOR parity ----
    // state is layout B: n = (j'<<8) | t, j' bit3..0 = n bits 11..8
    float p[16];
    #pragma unroll
    for (int r = 0; r < 8; ++r) {
        const v2f pp = re[r]*re[r] + im[r]*im[r];
        p[r] = pp.x; p[r + 8] = pp.y;
    }
    float A0 = 0.f, A1 = 0.f, A2 = 0.f, A3 = 0.f;
    #pragma unroll
    for (int jp = 0; jp < 16; ++jp) {
        const int b3 = (jp >> 3) & 1;
        const int s1 = b3 ^ ((jp >> 2) & 1);
        const int s2 = s1 ^ ((jp >> 1) & 1);
        const int s3 = s2 ^ (jp & 1);
        A0 += b3 ? -p[jp] : p[jp];
        A1 += s1 ? -p[jp] : p[jp];
        A2 += s2 ? -p[jp] : p[jp];
        A3 += s3 ? -p[jp] : p[jp];
    }
    float vals[8];
    vals[0] = A0; vals[1] = A1; vals[2] = A2; vals[3] = A3;
    const int t7 = (t >> 7) & 1, t6 = (t >> 6) & 1, t5 = (t >> 5) & 1, t4 = (t >> 4) & 1;
    vals[4] = t7                ? -A3 : A3;
    vals[5] = (t7^t6)           ? -A3 : A3;
    vals[6] = (t7^t6^t5)        ? -A3 : A3;
    vals[7] = (t7^t6^t5^t4)     ? -A3 : A3;

    const int lane = t & 63, wv = t >> 6;
    #pragma unroll
    for (int i = 0; i < 8; ++i) {
        float v = vals[i];
        #pragma unroll
        for (int off = 32; off; off >>= 1) v += __shfl_xor(v, off, 64);
        if (lane == 0) sred[wv * 8 + i] = v;
    }
    __syncthreads();
    if (t < 8) {
        const float r = sred[t] + sred[8 + t] + sred[16 + t] + sred[24 + t];
        out[b * 8 + t] = r * 3.14159265358979323846f;
    }
}

extern "C" void kernel_launch(void* const* d_in, const int* in_sizes, int n_in,
                              void* d_out, int out_size, void* d_ws, size_t ws_size,
                              hipStream_t stream) {
    const float* x = (const float*)d_in[0];   // [4096, 2]
    const float* w = (const float*)d_in[1];   // [4, 12, 3]
    float* out = (float*)d_out;               // [4096, 8]
    qnn_kernel<<<4096, 256, 0, stream>>>(x, w, out);
}

// Round 3
// 168.483 us; speedup vs baseline: 1.7346x; 1.1543x over previous
//
#include <hip/hip_runtime.h>
#include <math.h>

#define NW 12
#define NL 4
#define DIM 4096

typedef float v2f __attribute__((ext_vector_type(2)));
typedef float2 c32;

__device__ __forceinline__ c32 cmul(c32 a, c32 b) {
    return make_float2(a.x*b.x - a.y*b.y, a.x*b.y + a.y*b.x);
}
__device__ __forceinline__ c32 cadd(c32 a, c32 b) {
    return make_float2(a.x + b.x, a.y + b.y);
}

// pad 1 float2 per 16: PHYS(n) = n + (n>>4).
// Verified conflict-free (4 lanes per bank-pair) for A/B/C reads+writes and perm-gather.
__device__ __forceinline__ int PHYS(int i) { return i + (i >> 4); }

struct alignas(16) G { float c00x,c00y,c01x,c01y,c10x,c10y,c11x,c11y; };

// butterfly across the packing halves (local mask == 8): lo/hi of same v2f are the pair
__device__ __forceinline__ void apply_cross(v2f re[8], v2f im[8], const G g){
    const v2f Ax = {g.c00x, g.c11x}, Ay = {g.c00y, g.c11y};
    const v2f Bx = {g.c01x, g.c10x}, By = {g.c01y, g.c10y};
    #pragma unroll
    for (int r = 0; r < 8; ++r) {
        const v2f xr = re[r], xi = im[r];
        const v2f rs = {xr.y, xr.x}, is = {xi.y, xi.x};
        re[r] = xr*Ax - xi*Ay + rs*Bx - is*By;
        im[r] = xi*Ax + xr*Ay + is*Bx + rs*By;
    }
}
// butterfly on two pair-regs (local mask 4/2/1)
__device__ __forceinline__ void apply_pair(v2f re[8], v2f im[8], const G g, const int m){
    #pragma unroll
    for (int r = 0; r < 8; ++r) if (!(r & m)) {
        const v2f ar = re[r], ai = im[r], br = re[r|m], bi = im[r|m];
        re[r]   = ar*g.c00x - ai*g.c00y + br*g.c01x - bi*g.c01y;
        im[r]   = ai*g.c00x + ar*g.c00y + bi*g.c01x + br*g.c01y;
        re[r|m] = ar*g.c10x - ai*g.c10y + br*g.c11x - bi*g.c11y;
        im[r|m] = ai*g.c10x + ar*g.c10y + bi*g.c11x + br*g.c11y;
    }
}
// apply 4 gates on the 4 local bits; ug4[0] acts on the packing bit (mask 8)
__device__ __forceinline__ void seg4(v2f re[8], v2f im[8], const G* ug4){
    apply_cross(re, im, ug4[0]);
    apply_pair (re, im, ug4[1], 4);
    apply_pair (re, im, ug4[2], 2);
    apply_pair (re, im, ug4[3], 1);
}

__global__ __launch_bounds__(256) void qnn_kernel(const float* __restrict__ x,
                                                  const float* __restrict__ w,
                                                  float* __restrict__ out)
{
    __shared__ float2 st[DIM + (DIM >> 4)];  // 4352 * 8 B = 34 KB
    __shared__ G ug[NL * NW];
    __shared__ float sred[32];

    const int b = blockIdx.x;
    const int t = threadIdx.x;
    const int th = t >> 4, tl = t & 15;

    // ---- build fused per-(layer,wire) gate: U = Rz(w2)*Ry(w1)*Rx(w0)*Enc ----
    if (t < NL * NW) {
        const int wire = t % NW;
        const float ang = (wire & 1) ? x[b * 2 + 1] : x[b * 2 + 0];
        float se, ce;
        sincosf(0.5f * ang, &se, &ce);
        c32 E0, E1, E2, E3;
        if ((wire & 1) == 0) {            // Rx(x0)
            E0 = make_float2(ce, 0.f);  E1 = make_float2(0.f, -se);
            E2 = make_float2(0.f, -se); E3 = make_float2(ce, 0.f);
        } else {                          // Ry(x1)
            E0 = make_float2(ce, 0.f);  E1 = make_float2(-se, 0.f);
            E2 = make_float2(se, 0.f);  E3 = make_float2(ce, 0.f);
        }
        const float w0 = w[t * 3 + 0];
        const float w1 = w[t * 3 + 1];
        const float w2 = w[t * 3 + 2];
        float s0, c0; sincosf(0.5f * w0, &s0, &c0);
        const c32 rx00 = make_float2(c0, 0.f), rx01 = make_float2(0.f, -s0);
        c32 A0 = cadd(cmul(rx00, E0), cmul(rx01, E2));
        c32 A1 = cadd(cmul(rx00, E1), cmul(rx01, E3));
        c32 A2 = cadd(cmul(rx01, E0), cmul(rx00, E2));
        c32 A3 = cadd(cmul(rx01, E1), cmul(rx00, E3));
        float s1, c1; sincosf(0.5f * w1, &s1, &c1);
        c32 B0 = make_float2(c1*A0.x - s1*A2.x, c1*A0.y - s1*A2.y);
        c32 B1 = make_float2(c1*A1.x - s1*A3.x, c1*A1.y - s1*A3.y);
        c32 B2 = make_float2(s1*A0.x + c1*A2.x, s1*A0.y + c1*A2.y);
        c32 B3 = make_float2(s1*A1.x + c1*A3.x, s1*A1.y + c1*A3.y);
        float s2, c2; sincosf(0.5f * w2, &s2, &c2);
        const c32 em = make_float2(c2, -s2), ep = make_float2(c2, s2);
        const c32 u00 = cmul(em, B0), u01 = cmul(em, B1);
        const c32 u10 = cmul(ep, B2), u11 = cmul(ep, B3);
        G gg; gg.c00x=u00.x; gg.c00y=u00.y; gg.c01x=u01.x; gg.c01y=u01.y;
              gg.c10x=u10.x; gg.c10y=u10.y; gg.c11x=u11.x; gg.c11y=u11.y;
        ug[t] = gg;
    }
    __syncthreads();

    // ---- layer 0 analytically: product state then CNOT (gray) baked into A layout ----
    // layout A: n = t*16 + j; pack along j bit3: re[r].x = amp(j=r), re[r].y = amp(j=r+8)
    v2f re[8], im[8];
    {
        const int u = (t ^ (t >> 1)) & 255;     // n bits 11..4 (wires 0..7)
        c32 Pb = make_float2(1.f, 0.f);
        #pragma unroll
        for (int wq = 0; wq < 8; ++wq) {
            const G& gg = ug[wq];
            const int bit = (u >> (7 - wq)) & 1;
            const c32 c = bit ? make_float2(gg.c10x, gg.c10y)
                              : make_float2(gg.c00x, gg.c00y);
            Pb = cmul(Pb, c);
        }
        c32 c8[2]  = { make_float2(ug[8].c00x,  ug[8].c00y),  make_float2(ug[8].c10x,  ug[8].c10y) };
        c32 c9[2]  = { make_float2(ug[9].c00x,  ug[9].c00y),  make_float2(ug[9].c10x,  ug[9].c10y) };
        c32 cA[2]  = { make_float2(ug[10].c00x, ug[10].c00y), make_float2(ug[10].c10x, ug[10].c10y) };
        c32 cB[2]  = { make_float2(ug[11].c00x, ug[11].c00y), make_float2(ug[11].c10x, ug[11].c10y) };
        c32 L2[4], T4[4];
        #pragma unroll
        for (int k = 0; k < 4; ++k) {
            L2[k] = cmul(c8[(k >> 1) & 1], c9[k & 1]);
            T4[k] = cmul(cA[(k >> 1) & 1], cB[k & 1]);
        }
        const int t0 = t & 1;
        #pragma unroll
        for (int j = 0; j < 16; ++j) {
            const int l0 = j ^ (j >> 1);
            const c32 Lsel = t0 ? L2[((l0 >> 2) & 3) ^ 2] : L2[(l0 >> 2) & 3];
            const c32 amp = cmul(Pb, cmul(Lsel, T4[l0 & 3]));
            const int r = j & 7;
            if (j < 8) { re[r].x = amp.x; im[r].x = amp.y; }
            else       { re[r].y = amp.x; im[r].y = amp.y; }
        }
    }

    // ---- layers 1..3: three LDS-relayout segments, no shuffles ----
    for (int layer = 1; layer < NL; ++layer) {
        const int gbase = layer * NW;

        // segment A: wires 8..11 on local bits (wire 8 = packing bit)
        seg4(re, im, &ug[gbase + 8]);

        // T1: A -> C
        if (layer > 1) __syncthreads();   // protect prior layer's perm-gather reads
        #pragma unroll
        for (int r = 0; r < 8; ++r) {
            st[17*t + r]     = make_float2(re[r].x, im[r].x);
            st[17*t + 8 + r] = make_float2(re[r].y, im[r].y);
        }
        __syncthreads();
        #pragma unroll
        for (int r = 0; r < 8; ++r) {
            // C: n = 256*th + 16*j + tl  -> PHYS = 272*th + 17*j + tl
            const float2 lo = st[272*th + 17*r + tl];
            const float2 hi = st[272*th + 17*(r + 8) + tl];
            v2f vr; vr.x = lo.x; vr.y = hi.x; re[r] = vr;
            v2f vi; vi.x = lo.y; vi.y = hi.y; im[r] = vi;
        }

        // segment C: wires 4..7 (wire 4 = packing bit)
        seg4(re, im, &ug[gbase + 4]);

        // T2: C -> B (write back to slots just read -> no pre-sync)
        #pragma unroll
        for (int r = 0; r < 8; ++r) {
            st[272*th + 17*r + tl]       = make_float2(re[r].x, im[r].x);
            st[272*th + 17*(r + 8) + tl] = make_float2(re[r].y, im[r].y);
        }
        __syncthreads();
        #pragma unroll
        for (int r = 0; r < 8; ++r) {
            // B: n = (j<<8) | t -> PHYS = 272*j + t + th
            const float2 lo = st[272*r + t + th];
            const float2 hi = st[272*(r + 8) + t + th];
            v2f vr; vr.x = lo.x; vr.y = hi.x; re[r] = vr;
            v2f vi; vi.x = lo.y; vi.y = hi.y; im[r] = vi;
        }

        // segment B: wires 0..3 (wire 0 = packing bit)
        seg4(re, im, &ug[gbase + 0]);

        if (layer < NL - 1) {
            // T3: B -> A with CNOT perm fused (new[n] = old[n ^ (n>>1)])
            #pragma unroll
            for (int r = 0; r < 8; ++r) {
                st[272*r + t + th]       = make_float2(re[r].x, im[r].x);
                st[272*(r + 8) + t + th] = make_float2(re[r].y, im[r].y);
            }
            __syncthreads();
            #pragma unroll
            for (int r = 0; r < 8; ++r) {
                const int nlo = (t << 4) | r;
                const int nhi = (t << 4) | (r + 8);
                const int slo = nlo ^ (nlo >> 1);
                const int shi = nhi ^ (nhi >> 1);
                const float2 lo = st[slo + (slo >> 4)];
                const float2 hi = st[shi + (shi >> 4)];
                v2f vr; vr.x = lo.x; vr.y = hi.x; re[r] = vr;
                v2f vi; vi.x = lo.y; vi.y = hi.y; im[r] = vi;
            }
        }
    }

    // ---- reduction; final CNOT folded into signs (prefix-XOR parity) ----
    // state is layout B: n = (j'<<8) | t
    float p[16];
    #pragma unroll
    for (int r = 0; r < 8; ++r) {
        const v2f pp = re[r]*re[r] + im[r]*im[r];
        p[r] = pp.x; p[r + 8] = pp.y;
    }
    float A0 = 0.f, A1 = 0.f, A2 = 0.f, A3 = 0.f;
    #pragma unroll
    for (int jp = 0; jp < 16; ++jp) {
        const int b3 = (jp >> 3) & 1;
        const int s1 = b3 ^ ((jp >> 2) & 1);
        const int s2 = s1 ^ ((jp >> 1) & 1);
        const int s3 = s2 ^ (jp & 1);
        A0 += b3 ? -p[jp] : p[jp];
        A1 += s1 ? -p[jp] : p[jp];
        A2 += s2 ? -p[jp] : p[jp];
        A3 += s3 ? -p[jp] : p[jp];
    }
    float vals[8];
    vals[0] = A0; vals[1] = A1; vals[2] = A2; vals[3] = A3;
    const int t7 = (t >> 7) & 1, t6 = (t >> 6) & 1, t5 = (t >> 5) & 1, t4 = (t >> 4) & 1;
    vals[4] = t7                ? -A3 : A3;
    vals[5] = (t7^t6)           ? -A3 : A3;
    vals[6] = (t7^t6^t5)        ? -A3 : A3;
    vals[7] = (t7^t6^t5^t4)     ? -A3 : A3;

    const int lane = t & 63, wv = t >> 6;
    #pragma unroll
    for (int i = 0; i < 8; ++i) {
        float v = vals[i];
        #pragma unroll
        for (int off = 32; off; off >>= 1) v += __shfl_xor(v, off, 64);
        if (lane == 0) sred[wv * 8 + i] = v;
    }
    __syncthreads();
    if (t < 8) {
        const float r = sred[t] + sred[8 + t] + sred[16 + t] + sred[24 + t];
        out[b * 8 + t] = r * 3.14159265358979323846f;
    }
}

extern "C" void kernel_launch(void* const* d_in, const int* in_sizes, int n_in,
                              void* d_out, int out_size, void* d_ws, size_t ws_size,
                              hipStream_t stream) {
    const float* x = (const float*)d_in[0];   // [4096, 2]
    const float* w = (const float*)d_in[1];   // [4, 12, 3]
    float* out = (float*)d_out;               // [4096, 8]
    qnn_kernel<<<4096, 256, 0, stream>>>(x, w, out);
}

// Round 4
// 164.316 us; speedup vs baseline: 1.7786x; 1.0254x over previous
//
#include <hip/hip_runtime.h>
#include <math.h>

#define NW 12
#define NL 4
#define DIM 4096

typedef float v2f __attribute__((ext_vector_type(2)));   // one amp: {re, im}

__device__ __forceinline__ v2f cmul(v2f a, v2f b){
    v2f d; d.x = a.x*b.x - a.y*b.y; d.y = a.x*b.y + a.y*b.x; return d;
}

// ---- packed complex primitives (guaranteed v_pk_* codegen) ----
// d = { a.re*u.re, a.im*u.re }
__device__ __forceinline__ v2f cx_mul_re(v2f a, v2f u){
    v2f d;
    asm("v_pk_mul_f32 %0, %1, %2 op_sel_hi:[1,0]"
        : "=v"(d) : "v"(a), "v"(u));
    return d;
}
// d = acc + { a.re*u.re, a.im*u.re }
__device__ __forceinline__ v2f cx_fma_re(v2f a, v2f u, v2f acc){
    v2f d;
    asm("v_pk_fma_f32 %0, %1, %2, %3 op_sel_hi:[1,0,1]"
        : "=v"(d) : "v"(a), "v"(u), "v"(acc));
    return d;
}
// d = acc + { -a.im*u.im, a.re*u.im }   (the i*u.im cross term)
__device__ __forceinline__ v2f cx_fma_im(v2f a, v2f u, v2f acc){
    v2f d;
    asm("v_pk_fma_f32 %0, %1, %2, %3 op_sel:[1,1,0] op_sel_hi:[0,1,1] neg_lo:[0,1,0]"
        : "=v"(d) : "v"(a), "v"(u), "v"(acc));
    return d;
}

struct alignas(16) G { v2f u00, u01, u10, u11; };

// butterfly over the 16 register-resident amps on local bit mask m
__device__ __forceinline__ void bflys(v2f s[16], const G& g, const int m){
    #pragma unroll
    for (int r = 0; r < 16; ++r) if (!(r & m)) {
        const v2f a = s[r], b = s[r|m];
        v2f na = cx_fma_im(a, g.u00, cx_mul_re(a, g.u00));
        na     = cx_fma_im(b, g.u01, cx_fma_re(b, g.u01, na));
        v2f nb = cx_fma_im(a, g.u10, cx_mul_re(a, g.u10));
        nb     = cx_fma_im(b, g.u11, cx_fma_re(b, g.u11, nb));
        s[r] = na; s[r|m] = nb;
    }
}
__device__ __forceinline__ void seg4(v2f s[16], const G* g4){
    bflys(s, g4[0], 8);
    bflys(s, g4[1], 4);
    bflys(s, g4[2], 2);
    bflys(s, g4[3], 1);
}

__global__ __launch_bounds__(256) void qnn_kernel(const float* __restrict__ x,
                                                  const float* __restrict__ w,
                                                  float* __restrict__ out)
{
    __shared__ v2f st[DIM + (DIM >> 4)];   // 4352 * 8 B = 34 KB, PHYS(i)=i+(i>>4)
    __shared__ G ug[NL * NW];
    __shared__ float sred[32];

    const int b = blockIdx.x;
    const int t = threadIdx.x;
    const int th = t >> 4, tl = t & 15;

    // ---- build fused per-(layer,wire) gate: U = Rz(w2)*Ry(w1)*Rx(w0)*Enc ----
    if (t < NL * NW) {
        const int wire = t % NW;
        const float ang = (wire & 1) ? x[b * 2 + 1] : x[b * 2 + 0];
        float se, ce;
        sincosf(0.5f * ang, &se, &ce);
        v2f E0, E1, E2, E3;
        if ((wire & 1) == 0) {            // Rx(x0)
            E0 = (v2f){ce, 0.f};  E1 = (v2f){0.f, -se};
            E2 = (v2f){0.f, -se}; E3 = (v2f){ce, 0.f};
        } else {                          // Ry(x1)
            E0 = (v2f){ce, 0.f};  E1 = (v2f){-se, 0.f};
            E2 = (v2f){se, 0.f};  E3 = (v2f){ce, 0.f};
        }
        const float w0 = w[t * 3 + 0];
        const float w1 = w[t * 3 + 1];
        const float w2 = w[t * 3 + 2];
        float s0, c0; sincosf(0.5f * w0, &s0, &c0);
        const v2f rx00 = (v2f){c0, 0.f}, rx01 = (v2f){0.f, -s0};
        v2f A0 = cmul(rx00, E0) + cmul(rx01, E2);
        v2f A1 = cmul(rx00, E1) + cmul(rx01, E3);
        v2f A2 = cmul(rx01, E0) + cmul(rx00, E2);
        v2f A3 = cmul(rx01, E1) + cmul(rx00, E3);
        float s1, c1; sincosf(0.5f * w1, &s1, &c1);
        v2f B0 = c1*A0 - s1*A2;
        v2f B1 = c1*A1 - s1*A3;
        v2f B2 = s1*A0 + c1*A2;
        v2f B3 = s1*A1 + c1*A3;
        float s2, c2; sincosf(0.5f * w2, &s2, &c2);
        const v2f em = (v2f){c2, -s2}, ep = (v2f){c2, s2};
        G gg;
        gg.u00 = cmul(em, B0); gg.u01 = cmul(em, B1);
        gg.u10 = cmul(ep, B2); gg.u11 = cmul(ep, B3);
        ug[t] = gg;
    }
    __syncthreads();

    // ---- layer 0 analytically: product state, CNOT(gray) baked into A layout ----
    // layout A: s[j] = amp at n = 16t + j
    v2f s[16];
    {
        const int u = (t ^ (t >> 1)) & 255;     // gray n bits 11..4 (wires 0..7)
        v2f Pb = (v2f){1.f, 0.f};
        #pragma unroll
        for (int wq = 0; wq < 8; ++wq) {
            const int bit = (u >> (7 - wq)) & 1;
            Pb = cmul(Pb, bit ? ug[wq].u10 : ug[wq].u00);
        }
        v2f L2[4], T4[4];
        #pragma unroll
        for (int k = 0; k < 4; ++k) {
            L2[k] = cmul(((k >> 1) & 1) ? ug[8].u10  : ug[8].u00,
                         (k & 1)        ? ug[9].u10  : ug[9].u00);
            T4[k] = cmul(((k >> 1) & 1) ? ug[10].u10 : ug[10].u00,
                         (k & 1)        ? ug[11].u10 : ug[11].u00);
        }
        const int t0 = t & 1;
        #pragma unroll
        for (int j = 0; j < 16; ++j) {
            const int l0 = j ^ (j >> 1);
            const v2f Lsel = L2[((l0 >> 2) & 3) ^ (t0 ? 2 : 0)];
            s[j] = cmul(Pb, cmul(Lsel, T4[l0 & 3]));
        }
    }

    // perm-gather indices for T3 (loop-invariant)
    int pidx[16];
    #pragma unroll
    for (int r = 0; r < 16; ++r) {
        const int n = (t << 4) | r;
        const int g = n ^ (n >> 1);
        pidx[r] = g + (g >> 4);
    }

    // ---- layers 1..3: three LDS-relayout segments, all-packed butterflies ----
    for (int layer = 1; layer < NL; ++layer) {
        const int gbase = layer * NW;

        // segment A: wires 8..11 on local bits 3..0
        seg4(s, &ug[gbase + 8]);

        // T1: A -> C
        if (layer > 1) __syncthreads();   // protect prior layer's perm-gather reads
        #pragma unroll
        for (int r = 0; r < 16; ++r) st[17*t + r] = s[r];
        __syncthreads();
        #pragma unroll
        for (int r = 0; r < 16; ++r) s[r] = st[272*th + 17*r + tl];

        // segment C: wires 4..7
        seg4(s, &ug[gbase + 4]);

        // T2: C -> B (write back to slots just read -> no pre-sync)
        #pragma unroll
        for (int r = 0; r < 16; ++r) st[272*th + 17*r + tl] = s[r];
        __syncthreads();
        #pragma unroll
        for (int r = 0; r < 16; ++r) s[r] = st[272*r + t + th];

        // segment B: wires 0..3
        seg4(s, &ug[gbase + 0]);

        if (layer < NL - 1) {
            // T3: B -> A with CNOT perm fused (new[n] = old[n ^ (n>>1)])
            #pragma unroll
            for (int r = 0; r < 16; ++r) st[272*r + t + th] = s[r];
            __syncthreads();
            #pragma unroll
            for (int r = 0; r < 16; ++r) s[r] = st[pidx[r]];
        }
    }

    // ---- reduction; final CNOT folded into signs (partial Walsh tree) ----
    // state layout B: n = (j<<8) | t ; wires 0..3 signs from j, wires 4..7 from t
    float p[16];
    #pragma unroll
    for (int r = 0; r < 16; ++r) {
        const v2f q = s[r] * s[r];
        p[r] = q.x + q.y;
    }
    float s0[8], d0[8];
    #pragma unroll
    for (int k = 0; k < 8; ++k) { s0[k] = p[2*k] + p[2*k+1]; d0[k] = p[2*k] - p[2*k+1]; }
    float s1[4], ds1[4], dd1[4];
    #pragma unroll
    for (int k = 0; k < 4; ++k) {
        s1[k]  = s0[2*k] + s0[2*k+1];
        ds1[k] = s0[2*k] - s0[2*k+1];
        dd1[k] = d0[2*k] - d0[2*k+1];
    }
    const float A0 = (s1[0]  + s1[1])  - (s1[2]  + s1[3]);   // sign = b3
    const float A1 = (s1[0]  - s1[1])  - (s1[2]  - s1[3]);   // sign = b3^b2
    const float A2 = (ds1[0] - ds1[1]) - (ds1[2] - ds1[3]);  // sign = b3^b2^b1
    const float A3 = (dd1[0] - dd1[1]) - (dd1[2] - dd1[3]);  // sign = parity(j)

    float vals[8];
    vals[0] = A0; vals[1] = A1; vals[2] = A2; vals[3] = A3;
    const int t7 = (t >> 7) & 1, t6 = (t >> 6) & 1, t5 = (t >> 5) & 1, t4 = (t >> 4) & 1;
    vals[4] = t7            ? -A3 : A3;
    vals[5] = (t7^t6)       ? -A3 : A3;
    vals[6] = (t7^t6^t5)    ? -A3 : A3;
    vals[7] = (t7^t6^t5^t4) ? -A3 : A3;

    const int lane = t & 63, wv = t >> 6;
    #pragma unroll
    for (int i = 0; i < 8; ++i) {
        float v = vals[i];
        #pragma unroll
        for (int off = 32; off; off >>= 1) v += __shfl_xor(v, off, 64);
        if (lane == 0) sred[wv * 8 + i] = v;
    }
    __syncthreads();
    if (t < 8) {
        const float r = sred[t] + sred[8 + t] + sred[16 + t] + sred[24 + t];
        out[b * 8 + t] = r * 3.14159265358979323846f;
    }
}

extern "C" void kernel_launch(void* const* d_in, const int* in_sizes, int n_in,
                              void* d_out, int out_size, void* d_ws, size_t ws_size,
                              hipStream_t stream) {
    const float* x = (const float*)d_in[0];   // [4096, 2]
    const float* w = (const float*)d_in[1];   // [4, 12, 3]
    float* out = (float*)d_out;               // [4096, 8]
    qnn_kernel<<<4096, 256, 0, stream>>>(x, w, out);
}